// Round 10
// baseline (266.855 us; speedup 1.0000x reference)
//
#include <hip/hip_runtime.h>
#include <hip/hip_bf16.h>

#define BATCH   4
#define SEQ     2048
#define DMODEL  1024
#define NHEADS  16
#define DHEAD   64
#define MROWS   (BATCH*SEQ)        // 8192
#define QKV_N   (3*DMODEL)         // 3072
#define NEG_BIG (-1.0e30f)
#define WS_NEED ((size_t)MROWS * 2*DMODEL * sizeof(__hip_bfloat16))  // 33,554,432
#define SCALE_Q 0.18033688011112042f   // 0.125 * log2(e); folded into Q at projection

using bf16 = __hip_bfloat16;
typedef __attribute__((ext_vector_type(8))) short short8;
typedef __attribute__((ext_vector_type(4))) float floatx4;

// Static device buffers (module BSS; no hipMalloc)
__device__ __align__(16) unsigned short g_wqT[QKV_N * DMODEL];   // W_qkv^T bf16
__device__ __align__(16) unsigned short g_woT[DMODEL * DMODEL];  // W_out^T bf16
__device__ __align__(16) unsigned short g_xb [MROWS * DMODEL];   // x bf16

__device__ __forceinline__ unsigned short f2bf_rne(float f) {
    union { bf16 b; unsigned short u; } t;
    t.b = __float2bfloat16(f);
    return t.u;
}

// async global->LDS, 16B per lane; LDS dest = wave-uniform base + lane*16
__device__ __forceinline__ void gload_lds16(const void* g, void* l) {
    __builtin_amdgcn_global_load_lds(
        (const __attribute__((address_space(1))) unsigned*)g,
        (__attribute__((address_space(3))) unsigned*)l, 16, 0, 0);
}

// ---------------------------------------------------------------------------
// x fp32 -> bf16
// ---------------------------------------------------------------------------
__global__ __launch_bounds__(256) void cast_x(const float* __restrict__ x) {
    const size_t i = ((size_t)blockIdx.x*256 + threadIdx.x)*8;
    const float4 a = *(const float4*)(x + i);
    const float4 b = *(const float4*)(x + i + 4);
    union { uint4 u4; unsigned short us[8]; } o;
    o.us[0]=f2bf_rne(a.x); o.us[1]=f2bf_rne(a.y); o.us[2]=f2bf_rne(a.z); o.us[3]=f2bf_rne(a.w);
    o.us[4]=f2bf_rne(b.x); o.us[5]=f2bf_rne(b.y); o.us[6]=f2bf_rne(b.z); o.us[7]=f2bf_rne(b.w);
    *(uint4*)(g_xb + i) = o.u4;
}

// ---------------------------------------------------------------------------
// Weight transpose + cast (both weights in ONE launch):
// blocks [0,48): W_qkv fp32 [1024][3072] -> g_wqT [3072][1024]
// blocks [48,64): W_out fp32 [1024][1024] -> g_woT [1024][1024]
// ---------------------------------------------------------------------------
__global__ __launch_bounds__(256) void transcast_w2(
    const float* __restrict__ Wq, const float* __restrict__ Wo)
{
    const int bx = blockIdx.x;
    const float* W;
    unsigned short* dst;
    int N, n0;
    if (bx < 48) { W = Wq; dst = g_wqT; N = QKV_N;  n0 = bx * 64; }
    else         { W = Wo; dst = g_woT; N = DMODEL; n0 = (bx - 48) * 64; }
    const int k0 = blockIdx.y * 64;

    __shared__ unsigned short T[64][72];
    const int tid = threadIdx.x;
    const int r = tid >> 2, c0 = (tid & 3) * 16;

#pragma unroll
    for (int it = 0; it < 4; ++it) {
        const float4 v = *(const float4*)(W + (size_t)(k0 + r)*N + n0 + c0 + it*4);
        T[r][c0 + it*4 + 0] = f2bf_rne(v.x);
        T[r][c0 + it*4 + 1] = f2bf_rne(v.y);
        T[r][c0 + it*4 + 2] = f2bf_rne(v.z);
        T[r][c0 + it*4 + 3] = f2bf_rne(v.w);
    }
    __syncthreads();
    const int nr = tid >> 2, kc0 = (tid & 3) * 16;
#pragma unroll
    for (int it = 0; it < 2; ++it) {
        union { uint4 u4; unsigned short us[8]; } o;
#pragma unroll
        for (int j = 0; j < 8; j++) o.us[j] = T[kc0 + it*8 + j][nr];
        *(uint4*)(dst + (size_t)(n0 + nr)*DMODEL + k0 + kc0 + it*8) = o.u4;
    }
}

// ---------------------------------------------------------------------------
// qkv_proj: 256x256 BK=64, 4-phase/K-tile deep-pipelined MFMA GEMM.
// Round-9 audit: old stage order had a CROSS-WAVE RACE (waves read rg 8-11
// kh0 in p0, staged by other waves' unconfirmed A1 loads) plus one shallow
// (1-phase) wait. Fixed kh-split schedule: wave w stages
//   p0: A(w,kh0),A(8+w,kh0)   p1: B(2w,kh0),B(2w+1,kh0)
//   p2: A(w,kh1),A(8+w,kh1)   p3: B(2w,kh1),B(2w+1,kh1)
// Reads: p0=(mh0,kh0) p1=(mh1,kh0) p2=(mh0,kh1) p3=(mh1,kh1).
// Ledger (8 loads/wave/tile; queue entering p0(t) = {Akh1(t),Bkh1(t)}):
//  p1-end vmcnt(4): drains Akh1(t),Bkh1(t) [3-4 phases old] before p2 reads.
//  p3-end vmcnt(4): drains Akh0(t+1),Bkh0(t+1) [3-4 phases] before p0(t+1).
// Cross-wave safe: every wave confirms exactly the subtiles IT staged via
// its own vmcnt BEFORE the barrier that precedes any reader.
// Tail t=15: p1-end vmcnt(0) (4 stale loads), p3-end: none.
// ---------------------------------------------------------------------------
__global__ __launch_bounds__(512, 2) void qkv_proj(
    const float* __restrict__ bias, bf16* __restrict__ Qo,
    bf16* __restrict__ Ko, bf16* __restrict__ VT)
{
    const unsigned short* A  = g_xb;
    const unsigned short* BT = g_wqT;
    constexpr int NBN = 12;            // 3072/256
    constexpr int NWG = 32 * NBN;      // 384

    __shared__ __align__(16) char smem[131072];   // A: 2x32KB @0; B: 2x32KB @64K
    char* const sA = smem;
    char* const sB = smem + 65536;

    // XCD-aware swizzle (NWG%8==0): consecutive blocks share bm, sweep bn
    const int orig = blockIdx.x;
    const int wgid = (orig & 7) * (NWG >> 3) + (orig >> 3);
    const int bm = wgid / NBN, bn = wgid % NBN;

    const int tid  = threadIdx.x;
    const int w    = tid >> 6, lane = tid & 63;
    const int m16  = lane & 15, quad = lane >> 4;
    const int rw   = w >> 2, cw = w & 3;          // 2M x 4N

    // staging lane decomposition: slot chunk (r,c) holds data chunk c^((r>>1)&3)
    const int rL = lane >> 2;
    const int cD = (lane & 3) ^ ((lane >> 3) & 3);
    const unsigned short* gA = A  + (size_t)(bm*256 + rL)*DMODEL + cD*8;
    const unsigned short* gB = BT + (size_t)(bn*256 + rL)*DMODEL + cD*8;

    // frag-read lane offset (swizzled)
    const int laneRd = m16*64 + (quad ^ ((m16 >> 1) & 3))*16;

    floatx4 acc[8][4];   // [mf][nf]
#pragma unroll
    for (int i = 0; i < 8; ++i)
#pragma unroll
        for (int j = 0; j < 4; ++j) {
            acc[i][j][0]=0.f; acc[i][j][1]=0.f; acc[i][j][2]=0.f; acc[i][j][3]=0.f;
        }

    auto stA = [&](int buf, int rg, int kh, int k0) {
        gload_lds16(gA + (size_t)(rg*16)*DMODEL + k0 + kh*32,
                    sA + buf*32768 + (rg*2 + kh)*1024);
    };
    auto stB = [&](int buf, int rg, int kh, int k0) {
        gload_lds16(gB + (size_t)(rg*16)*DMODEL + k0 + kh*32,
                    sB + buf*32768 + (rg*2 + kh)*1024);
    };

    // ---- prologue: tile 0 -> buf 0 (same per-wave order as steady state)
    stA(0, w, 0, 0);   stA(0, 8+w, 0, 0);
    stB(0, 2*w, 0, 0); stB(0, 2*w+1, 0, 0);
    stA(0, w, 1, 0);   stA(0, 8+w, 1, 0);
    stB(0, 2*w, 1, 0); stB(0, 2*w+1, 1, 0);
    asm volatile("s_waitcnt vmcnt(0)" ::: "memory");
    __builtin_amdgcn_s_barrier();

    const int NT = DMODEL / 64;   // 16
    for (int t = 0; t < NT; ++t) {
        const int  buf = t & 1;
        const int  k1  = (t + 1) * 64;
        const bool st  = (t + 1 < NT);
        char* const Ab = sA + buf*32768;
        char* const Bb = sB + buf*32768;

        short8 bf[4], af[4];

        // ============ p0: (mh0, kh0) ============
#pragma unroll
        for (int j = 0; j < 4; ++j)
            bf[j] = *(const short8*)(Bb + ((cw*4 + j)*2 + 0)*1024 + laneRd);
#pragma unroll
        for (int i = 0; i < 4; ++i)
            af[i] = *(const short8*)(Ab + ((rw*8 + i)*2 + 0)*1024 + laneRd);
        if (st) { stA(buf^1, w, 0, k1); stA(buf^1, 8+w, 0, k1); }
        __builtin_amdgcn_s_barrier();
        __builtin_amdgcn_s_setprio(1);
#pragma unroll
        for (int i = 0; i < 4; ++i)
#pragma unroll
            for (int j = 0; j < 4; ++j)
                acc[i][j] = __builtin_amdgcn_mfma_f32_16x16x32_bf16(af[i], bf[j], acc[i][j], 0, 0, 0);
        __builtin_amdgcn_s_setprio(0);
        __builtin_amdgcn_s_barrier();

        // ============ p1: (mh1, kh0) ============
#pragma unroll
        for (int i = 0; i < 4; ++i)
            af[i] = *(const short8*)(Ab + ((rw*8 + 4 + i)*2 + 0)*1024 + laneRd);
        if (st) { stB(buf^1, 2*w, 0, k1); stB(buf^1, 2*w+1, 0, k1); }
        __builtin_amdgcn_s_barrier();
        __builtin_amdgcn_s_setprio(1);
#pragma unroll
        for (int i = 0; i < 4; ++i)
#pragma unroll
            for (int j = 0; j < 4; ++j)
                acc[4+i][j] = __builtin_amdgcn_mfma_f32_16x16x32_bf16(af[i], bf[j], acc[4+i][j], 0, 0, 0);
        __builtin_amdgcn_s_setprio(0);
        if (st) { asm volatile("s_waitcnt vmcnt(4)" ::: "memory"); }
        else    { asm volatile("s_waitcnt vmcnt(0)" ::: "memory"); }
        __builtin_amdgcn_s_barrier();

        // ============ p2: (mh0, kh1) ============
#pragma unroll
        for (int j = 0; j < 4; ++j)
            bf[j] = *(const short8*)(Bb + ((cw*4 + j)*2 + 1)*1024 + laneRd);
#pragma unroll
        for (int i = 0; i < 4; ++i)
            af[i] = *(const short8*)(Ab + ((rw*8 + i)*2 + 1)*1024 + laneRd);
        if (st) { stA(buf^1, w, 1, k1); stA(buf^1, 8+w, 1, k1); }
        __builtin_amdgcn_s_barrier();
        __builtin_amdgcn_s_setprio(1);
#pragma unroll
        for (int i = 0; i < 4; ++i)
#pragma unroll
            for (int j = 0; j < 4; ++j)
                acc[i][j] = __builtin_amdgcn_mfma_f32_16x16x32_bf16(af[i], bf[j], acc[i][j], 0, 0, 0);
        __builtin_amdgcn_s_setprio(0);
        __builtin_amdgcn_s_barrier();

        // ============ p3: (mh1, kh1) ============
#pragma unroll
        for (int i = 0; i < 4; ++i)
            af[i] = *(const short8*)(Ab + ((rw*8 + 4 + i)*2 + 1)*1024 + laneRd);
        if (st) { stB(buf^1, 2*w, 1, k1); stB(buf^1, 2*w+1, 1, k1); }
        __builtin_amdgcn_s_barrier();
        __builtin_amdgcn_s_setprio(1);
#pragma unroll
        for (int i = 0; i < 4; ++i)
#pragma unroll
            for (int j = 0; j < 4; ++j)
                acc[4+i][j] = __builtin_amdgcn_mfma_f32_16x16x32_bf16(af[i], bf[j], acc[4+i][j], 0, 0, 0);
        __builtin_amdgcn_s_setprio(0);
        if (st) {
            asm volatile("s_waitcnt vmcnt(4)" ::: "memory");
            __builtin_amdgcn_s_barrier();
        }
    }

    // ---- epilogue: seg = 0(Q,scaled) / 1(K) / 2(V transposed)
    float bv[4];
#pragma unroll
    for (int j = 0; j < 4; ++j)
        bv[j] = bias[bn*256 + cw*64 + j*16 + m16];

    const int seg = bn >> 2;
    if (seg < 2) {
        bf16* Cout = seg ? Ko : Qo;
        const float sc = seg ? 1.0f : SCALE_Q;
#pragma unroll
        for (int mf = 0; mf < 8; ++mf)
#pragma unroll
            for (int r = 0; r < 4; ++r) {
                const int gm = bm*256 + rw*128 + mf*16 + quad*4 + r;
#pragma unroll
                for (int j = 0; j < 4; ++j) {
                    const int cc = (bn*256 + cw*64 + j*16 + m16) & 1023;
                    Cout[(size_t)gm*DMODEL + cc] =
                        __float2bfloat16((acc[mf][j][r] + bv[j]) * sc);
                }
            }
    } else {
#pragma unroll
        for (int mf = 0; mf < 8; ++mf) {
            const int gm0 = bm*256 + rw*128 + mf*16 + quad*4;
            const int bb = gm0 >> 11, t0 = gm0 & 2047;
#pragma unroll
            for (int j = 0; j < 4; ++j) {
                const int cv = ((bn & 3)*256 + cw*64 + j*16 + m16);
                const int hh = cv >> 6, dd = cv & 63;
                union { unsigned long long u8; unsigned short us[4]; } o;
#pragma unroll
                for (int r = 0; r < 4; ++r)
                    o.us[r] = f2bf_rne(acc[mf][j][r] + bv[j]);
                *(unsigned long long*)(VT
                    + ((size_t)((bb*NHEADS + hh)*DHEAD + dd))*SEQ + t0) = o.u8;
            }
        }
    }
}

// ---------------------------------------------------------------------------
// out_proj: UNCHANGED 256x128 BK=64 2-phase kernel.
// ---------------------------------------------------------------------------
__global__ __launch_bounds__(512, 2) void out_proj(
    const void* __restrict__ Av, const float* __restrict__ bias, float* C)
{
    const unsigned short* A  = (const unsigned short*)Av;
    const unsigned short* BT = g_woT;
    constexpr int NBN = 8;
    constexpr int NWG = NBN * 32;

    __shared__ __align__(16) char smem[98304];  // A: 2x32KB @0; B: 2x16KB @65536
    char* const sA = smem;
    char* const sB = smem + 65536;

    const int orig = blockIdx.x;
    const int wgid = (orig & 7) * (NWG >> 3) + (orig >> 3);
    const int bm = wgid / NBN, bn = wgid % NBN;

    const int tid  = threadIdx.x;
    const int w    = tid >> 6, lane = tid & 63;
    const int m16  = lane & 15, quad = lane >> 4;
    const int rw   = w >> 1, cw = w & 1;

    const int rL = lane >> 2;
    const int cD = (lane & 3) ^ ((lane >> 3) & 3);
    const unsigned short* gA = A  + (size_t)(bm*256 + rL)*DMODEL + cD*8;
    const unsigned short* gB = BT + (size_t)(bn*128 + rL)*DMODEL + cD*8;

    const int laneRd = m16*64 + (quad ^ ((m16 >> 1) & 3))*16;

    floatx4 acc[2][2][4];
#pragma unroll
    for (int q = 0; q < 2; ++q)
#pragma unroll
        for (int i = 0; i < 2; ++i)
#pragma unroll
            for (int j = 0; j < 4; ++j) {
                acc[q][i][j][0]=0.f; acc[q][i][j][1]=0.f;
                acc[q][i][j][2]=0.f; acc[q][i][j][3]=0.f;
            }

    auto stageA = [&](int buf, int a, int k0) {
        const int rg = 4*a + (w >> 1), kh = w & 1;
        gload_lds16(gA + (size_t)(rg*16)*DMODEL + k0 + kh*32,
                    sA + buf*32768 + (rg*2 + kh)*1024);
    };
    auto stageB = [&](int buf, int b, int k0) {
        const int rg = 4*b + (w >> 1), kh = w & 1;
        gload_lds16(gB + (size_t)(rg*16)*DMODEL + k0 + kh*32,
                    sB + buf*16384 + (rg*2 + kh)*1024);
    };

    stageB(0, 0, 0); stageB(0, 1, 0);
    stageA(0, 0, 0); stageA(0, 1, 0); stageA(0, 2, 0); stageA(0, 3, 0);
    asm volatile("s_waitcnt vmcnt(0)" ::: "memory");
    __builtin_amdgcn_s_barrier();

    const int NT = DMODEL / 64;
    for (int t = 0; t < NT; ++t) {
        const int  buf = t & 1;
        const int  k1  = (t + 1) * 64;
        const bool st  = (t + 1 < NT);
        char* const Ab = sA + buf*32768;
        char* const Bb = sB + buf*16384;

        short8 bf[4][2], af[2][2];
#pragma unroll
        for (int j = 0; j < 4; ++j)
#pragma unroll
            for (int kh = 0; kh < 2; ++kh)
                bf[j][kh] = *(const short8*)(Bb + ((cw*4 + j)*2 + kh)*1024 + laneRd);
#pragma unroll
        for (int i = 0; i < 2; ++i)
#pragma unroll
            for (int kh = 0; kh < 2; ++kh)
                af[i][kh] = *(const short8*)(Ab + ((rw*2 + i)*2 + kh)*1024 + laneRd);

        if (st) { stageB(buf^1, 0, k1); stageB(buf^1, 1, k1);
                  stageA(buf^1, 0, k1); stageA(buf^1, 1, k1); }
        __builtin_amdgcn_s_barrier();

        __builtin_amdgcn_s_setprio(1);
#pragma unroll
        for (int i = 0; i < 2; ++i)
#pragma unroll
            for (int j = 0; j < 4; ++j) {
                acc[0][i][j] = __builtin_amdgcn_mfma_f32_16x16x32_bf16(
                    af[i][0], bf[j][0], acc[0][i][j], 0, 0, 0);
                acc[0][i][j] = __builtin_amdgcn_mfma_f32_16x16x32_bf16(
                    af[i][1], bf[j][1], acc[0][i][j], 0, 0, 0);
            }
        __builtin_amdgcn_s_setprio(0);

        if (st) { asm volatile("s_waitcnt vmcnt(4)" ::: "memory"); }
        else    { asm volatile("s_waitcnt vmcnt(0)" ::: "memory"); }
        __builtin_amdgcn_s_barrier();

#pragma unroll
        for (int i = 0; i < 2; ++i)
#pragma unroll
            for (int kh = 0; kh < 2; ++kh)
                af[i][kh] = *(const short8*)(Ab + ((8 + rw*2 + i)*2 + kh)*1024 + laneRd);

        if (st) { stageA(buf^1, 2, k1); stageA(buf^1, 3, k1); }
        __builtin_amdgcn_s_barrier();

        __builtin_amdgcn_s_setprio(1);
#pragma unroll
        for (int i = 0; i < 2; ++i)
#pragma unroll
            for (int j = 0; j < 4; ++j) {
                acc[1][i][j] = __builtin_amdgcn_mfma_f32_16x16x32_bf16(
                    af[i][0], bf[j][0], acc[1][i][j], 0, 0, 0);
                acc[1][i][j] = __builtin_amdgcn_mfma_f32_16x16x32_bf16(
                    af[i][1], bf[j][1], acc[1][i][j], 0, 0, 0);
            }
        __builtin_amdgcn_s_setprio(0);

        if (st) { asm volatile("s_waitcnt vmcnt(2)" ::: "memory"); }
        else    { asm volatile("s_waitcnt vmcnt(0)" ::: "memory"); }
        __builtin_amdgcn_s_barrier();
    }

    float bv[4];
#pragma unroll
    for (int j = 0; j < 4; ++j)
        bv[j] = bias[bn*128 + cw*64 + j*16 + m16];

#pragma unroll
    for (int q = 0; q < 2; ++q)
#pragma unroll
        for (int i = 0; i < 2; ++i)
#pragma unroll
            for (int r = 0; r < 4; ++r) {
                const int gm = bm*256 + q*128 + rw*32 + i*16 + quad*4 + r;
#pragma unroll
                for (int j = 0; j < 4; ++j) {
                    const int cc = bn*128 + cw*64 + j*16 + m16;
                    C[(size_t)gm*DMODEL + cc] = acc[q][i][j][r] + bv[j];
                }
            }
}

// ---------------------------------------------------------------------------
// MFMA flash attention v7 = v6 + softmax denominator via PV MFMA.
// V tile extended to 80 d-rows: row 64 = ones (bf16 1.0), rows 65-79 = 0,
// written ONCE (staging only touches rows 0-63). The PV product then yields
// l = sum_k P[k][q] in output row 64 (of[i][4][0] on quad==0 lanes), and it
// rescales by alpha together with O. Removes rs-sum (16 adds + 2 shfl) and
// lrow bookkeeping per i-group; adds 4 MFMA/tile on the 18%-utilized pipe.
// Denominator now sums the same bf16-rounded P used by the PV numerator.
// Grid/layout unchanged from v6 (1024 blocks, 3 blocks/CU, longest-first).
// ---------------------------------------------------------------------------
__global__ __launch_bounds__(256, 3) void attn_mfma7(
    const bf16* __restrict__ Qg, const bf16* __restrict__ Kg,
    const bf16* __restrict__ VTg, bf16* __restrict__ Og)
{
    __shared__ alignas(16) unsigned short Kt[2][64][72];   // [buf][key][d]
    __shared__ alignas(16) unsigned short Vt[80][72];      // [d'][key]; 64=ones
    __shared__ alignas(16) unsigned short Ps[4][32][72];   // [wave][q][key]

    const int L  = blockIdx.x;
    const int qt = 15 - (L >> 6);      // longest q-tiles dispatched first
    const int bh = L & 63;
    const int b  = bh >> 4, h = bh & 15;

    const int tid = threadIdx.x;
    const int w = tid >> 6, lane = tid & 63;
    const int m16 = lane & 15, quad = lane >> 4;
    const int sr = tid >> 2, sc0 = (tid & 3) * 8;
    const size_t bhs = (size_t)(b*NHEADS + h);

    const int nkt = 2*qt + 2;
    const int qrow0 = qt*128 + w*32;

    short8 qf[2][2];
#pragma unroll
    for (int i = 0; i < 2; ++i)
#pragma unroll
        for (int c = 0; c < 2; ++c)
            qf[i][c] = *(const short8*)(Qg + (size_t)(b*SEQ + qrow0 + i*16 + m16)*DMODEL
                                        + h*DHEAD + c*32 + quad*8);

    floatx4 of[2][5];
    float mrow[2];
#pragma unroll
    for (int i = 0; i < 2; ++i) {
        mrow[i] = NEG_BIG;
#pragma unroll
        for (int nt = 0; nt < 5; ++nt) { of[i][nt][0]=0.f; of[i][nt][1]=0.f; of[i][nt][2]=0.f; of[i][nt][3]=0.f; }
    }

    // ---- one-time: V' rows 64-79 (row 64 = 1.0 bf16, rest 0)
    for (int idx = tid; idx < 16*72; idx += 256) {
        const int r = idx / 72, c = idx % 72;
        Vt[64 + r][c] = (r == 0) ? (unsigned short)0x3F80 : (unsigned short)0;
    }

    // ---- stage tile 0
    {
        const bf16* kp = Kg  + (size_t)(b*SEQ + sr)*DMODEL + h*DHEAD + sc0;
        const bf16* vp = VTg + (bhs*DHEAD + sr)*SEQ + sc0;
        const uint4 a0 = *(const uint4*)kp, a1 = *(const uint4*)(kp + 32);
        const uint4 b0 = *(const uint4*)vp, b1 = *(const uint4*)(vp + 32);
        *(uint4*)&Kt[0][sr][sc0]      = a0;
        *(uint4*)&Kt[0][sr][sc0 + 32] = a1;
        *(uint4*)&Vt[sr][sc0]         = b0;
        *(uint4*)&Vt[sr][sc0 + 32]    = b1;
        __syncthreads();
    }

    for (int kt = 0; kt < nkt; ++kt) {
        const int buf = kt & 1;
        const int k064 = kt * 64;
        const bool pre = (kt + 1 < nkt);
        uint4 kr0, kr1, vr0, vr1;
        if (pre) {
            const bf16* kp = Kg  + (size_t)(b*SEQ + k064 + 64 + sr)*DMODEL + h*DHEAD + sc0;
            const bf16* vp = VTg + (bhs*DHEAD + sr)*SEQ + k064 + 64 + sc0;
            kr0 = *(const uint4*)kp; kr1 = *(const uint4*)(kp + 32);
            vr0 = *(const uint4*)vp; vr1 = *(const uint4*)(vp + 32);
        }

        // ---- S^T = K Q^T (16 MFMA): rows=key(quad*4+r, t4), cols=q(m16)
        floatx4 sf[2][4];
#pragma unroll
        for (int t4 = 0; t4 < 4; ++t4) {
            const short8 kf0 = *(const short8*)&Kt[buf][t4*16 + m16][quad*8];
            const short8 kf1 = *(const short8*)&Kt[buf][t4*16 + m16][32 + quad*8];
#pragma unroll
            for (int i = 0; i < 2; ++i) {
                floatx4 a; a[0]=0.f; a[1]=0.f; a[2]=0.f; a[3]=0.f;
                a = __builtin_amdgcn_mfma_f32_16x16x32_bf16(kf0, qf[i][0], a, 0, 0, 0);
                a = __builtin_amdgcn_mfma_f32_16x16x32_bf16(kf1, qf[i][1], a, 0, 0, 0);
                sf[i][t4] = a;
            }
        }

        // ---- online softmax (per lane = per q-column), defer-max
        const bool need_mask = (k064 + 63 > qrow0);
#pragma unroll
        for (int i = 0; i < 2; ++i) {
            if (need_mask) {
                const int qg = qrow0 + i*16 + m16;
#pragma unroll
                for (int t4 = 0; t4 < 4; ++t4)
#pragma unroll
                    for (int r = 0; r < 4; ++r)
                        if (k064 + t4*16 + quad*4 + r > qg) sf[i][t4][r] = NEG_BIG;
            }
            float mx = sf[i][0][0];
#pragma unroll
            for (int t4 = 0; t4 < 4; ++t4)
#pragma unroll
                for (int r = 0; r < 4; ++r) mx = fmaxf(mx, sf[i][t4][r]);
            mx = fmaxf(mx, __shfl_xor(mx, 16));
            mx = fmaxf(mx, __shfl_xor(mx, 32));

            // defer-max: rescale (O and l together) only on meaningful growth
            if (__any(mx > mrow[i] + 8.f)) {
                const float mnew  = fmaxf(mrow[i], mx);
                const float alpha = exp2f(mrow[i] - mnew);
                mrow[i] = mnew;
#pragma unroll
                for (int nt = 0; nt < 5; ++nt)
#pragma unroll
                    for (int r = 0; r < 4; ++r) of[i][nt][r] *= alpha;
            }

#pragma unroll
            for (int t4 = 0; t4 < 4; ++t4)
#pragma unroll
                for (int r = 0; r < 4; ++r)
                    sf[i][t4][r] = exp2f(sf[i][t4][r] - mrow[i]);

            // P^T -> LDS: 4 consecutive keys per b64 store
#pragma unroll
            for (int t4 = 0; t4 < 4; ++t4) {
                union { unsigned long long u8; unsigned short us[4]; } o;
#pragma unroll
                for (int r = 0; r < 4; ++r) o.us[r] = f2bf_rne(sf[i][t4][r]);
                *(unsigned long long*)&Ps[w][i*16 + m16][t4*16 + quad*4] = o.u8;
            }
        }

        // ---- O'^T += V'^T P^T (20 MFMA; nt=4 row-block accumulates l)
        short8 pf[2][2];
#pragma unroll
        for (int i = 0; i < 2; ++i)
#pragma unroll
            for (int c = 0; c < 2; ++c)
                pf[i][c] = *(const short8*)&Ps[w][i*16 + m16][c*32 + quad*8];
#pragma unroll
        for (int nt = 0; nt < 5; ++nt) {
            const short8 vf0 = *(const short8*)&Vt[nt*16 + m16][quad*8];
            const short8 vf1 = *(const short8*)&Vt[nt*16 + m16][32 + quad*8];
#pragma unroll
            for (int i = 0; i < 2; ++i) {
                of[i][nt] = __builtin_amdgcn_mfma_f32_16x16x32_bf16(vf0, pf[i][0], of[i][nt], 0, 0, 0);
                of[i][nt] = __builtin_amdgcn_mfma_f32_16x16x32_bf16(vf1, pf[i][1], of[i][nt], 0, 0, 0);
            }
        }

        // all waves done reading Vt before it is overwritten
        __syncthreads();
        if (pre) {
            *(uint4*)&Kt[buf^1][sr][sc0]      = kr0;
            *(uint4*)&Kt[buf^1][sr][sc0 + 32] = kr1;
            *(uint4*)&Vt[sr][sc0]             = vr0;
            *(uint4*)&Vt[sr][sc0 + 32]        = vr1;
        }
        __syncthreads();
    }

    // ---- normalize + store O: l for q=m16 lives in of[i][4][0] of lane m16
#pragma unroll
    for (int i = 0; i < 2; ++i) {
        const float lsum = __shfl(of[i][4][0], m16);
        const float rl = 1.f / fmaxf(lsum, 1e-20f);
        const size_t rowbase = (size_t)(b*SEQ + qrow0 + i*16 + m16)*DMODEL + h*DHEAD;
#pragma unroll
        for (int nt = 0; nt < 4; ++nt) {
            union { unsigned long long u8; unsigned short us[4]; } o;
#pragma unroll
            for (int r = 0; r < 4; ++r) o.us[r] = f2bf_rne(of[i][nt][r] * rl);
            *(unsigned long long*)(Og + rowbase + nt*16 + quad*4) = o.u8;
        }
    }
}

__global__ void diag_fill(float* out, int n, float val) {
    int i = blockIdx.x*blockDim.x + threadIdx.x;
    if (i < n) out[i] = val;
}

// ---------------------------------------------------------------------------
extern "C" void kernel_launch(void* const* d_in, const int* in_sizes, int n_in,
                              void* d_out, int out_size, void* d_ws, size_t ws_size,
                              hipStream_t stream) {
    const float* x     = (const float*)d_in[0];
    const float* W_qkv = (const float*)d_in[1];
    const float* b_qkv = (const float*)d_in[2];
    const float* W_out = (const float*)d_in[3];
    const float* b_out = (const float*)d_in[4];

    if (ws_size < WS_NEED) {
        const float val = 100.f + (float)(ws_size >> 20);
        diag_fill<<<(out_size + 255)/256, 256, 0, stream>>>((float*)d_out, out_size, val);
        return;
    }

    bf16* Qb  = (bf16*)d_out;                                // d_out lo: Q (pre-scaled)
    bf16* VTb = (bf16*)d_out + (size_t)MROWS*DMODEL;         // d_out hi: VT
    bf16* Kb  = (bf16*)d_ws;                                 // ws lo: K
    bf16* Ob  = (bf16*)d_ws + (size_t)MROWS*DMODEL;          // ws hi: O

    // 0) casts (both weight transposes fused into one launch)
    cast_x<<<MROWS*DMODEL/2048, 256, 0, stream>>>(x);
    {
        dim3 g(64, DMODEL/64);
        transcast_w2<<<g, 256, 0, stream>>>(W_qkv, W_out);
    }
    // 1) fused QKV projection (4-phase, race-fixed deep ledger)
    qkv_proj<<<384, 512, 0, stream>>>(b_qkv, Qb, Kb, VTb);
    // 2) flash attention v7 (l via PV MFMA)
    attn_mfma7<<<1024, 256, 0, stream>>>(Qb, Kb, VTb, Ob);
    // 3) output projection (unchanged)
    out_proj<<<256, 512, 0, stream>>>(Ob, b_out, (float*)d_out);
}